// Round 5
// baseline (392.921 us; speedup 1.0000x reference)
//
#include <hip/hip_runtime.h>

// LinearAttention fused pipeline for MI355X (gfx950) — round 9.
// r8 accounting: ~130 us of kernel time vs 199 us wall -> ~70 us of launch
// gaps across 5 serialized dispatches; each kernel latency-bound (25% HBM,
// 7% MFMA, 14% occ). r9: ONE kernel, grid 512 = 2 blocks/CU (proven r8
// occupancy point). Cross-block deps are per-batch only (16 peer blocks),
// implemented with device-scope atomic arrive/wait counters -> batches
// pipeline through {KV-ctx, Q-attn-O, GroupNorm} phases independently;
// K1/QAO phases of different resident blocks overlap on a CU. GroupNorm
// re-reads the block's OWN output region (XCD-L2 hot, no HBM re-read).
// k_wcast deleted: weight A-frags converted f32->bf16 in registers (same
// RNE f2bf -> bit-identical numerics).
//
// ws: ctx_u[32][4][32][32] f32 | Z[32][128] f32 | stats[32][2] f32 |
//     done1[32] u32 | done2[32] u32

#define B_   32
#define C_   128
#define N_   4096
#define H_   4
#define D_   32
#define HID  128
#define NB   64
#define TPB  4        // n-tiles per block
#define NSTRIP 16     // strips per batch (NSTRIP*TPB*NB == N_)
#define STV  72       // ek/v row stride (shorts)
#define STA  136      // eqT/attnT row stride (shorts)
#define SCT  40       // ctxT row stride (shorts)
#define SCALE 0.1767766952966369f
#define EPS  1e-5f

typedef __attribute__((ext_vector_type(8))) short short8;
typedef __attribute__((ext_vector_type(4))) short short4v;
typedef __attribute__((ext_vector_type(4))) float floatx4;

__device__ __forceinline__ short f2bf(float f) {   // RNE fp32 -> bf16
  unsigned u = __float_as_uint(f);
  u += 0x7FFFu + ((u >> 16) & 1u);
  return (short)(u >> 16);
}

// load the wave's c-quarter of x tile tt into registers (32 scalar f32,
// each instr coalesces 4 rows x 64B across the wave)
#define XLOAD(tt)                                                        \
  _Pragma("unroll")                                                      \
  for (int nt = 0; nt < 4; ++nt)                                         \
    _Pragma("unroll")                                                    \
    for (int j = 0; j < 8; ++j)                                          \
      xr[nt][j] = xw[(size_t)j * N_ + (size_t)(tt) * NB + nt * 16];

// convert + write this wave's 4 fragments (lane-linear b128, conflict-free)
#define XCVT(fragbuf)                                                    \
  _Pragma("unroll")                                                      \
  for (int nt = 0; nt < 4; ++nt) {                                       \
    short8 s;                                                            \
    _Pragma("unroll")                                                    \
    for (int j = 0; j < 8; ++j) s[j] = f2bf(xr[nt][j]);                  \
    *(short8*)&fragbuf[((w * 4 + nt) * 64 + L) * 8] = s;                 \
  }

// convert a weight matrix's A-frags f32 -> bf16 in registers
#define WFRAG(dst, Wsrc, LD)                                             \
  _Pragma("unroll")                                                      \
  for (int mt = 0; mt < 2; ++mt)                                         \
    _Pragma("unroll")                                                    \
    for (int ks = 0; ks < 4; ++ks) {                                     \
      const float* p_ = &Wsrc[(w * 32 + mt * 16 + l15) * LD + ks * 32 + q4 * 8]; \
      floatx4 a0_ = *(const floatx4*)p_;                                 \
      floatx4 a1_ = *(const floatx4*)(p_ + 4);                           \
      short8 s_;                                                         \
      s_[0] = f2bf(a0_[0]); s_[1] = f2bf(a0_[1]);                        \
      s_[2] = f2bf(a0_[2]); s_[3] = f2bf(a0_[3]);                        \
      s_[4] = f2bf(a1_[0]); s_[5] = f2bf(a1_[1]);                        \
      s_[6] = f2bf(a1_[2]); s_[7] = f2bf(a1_[3]);                        \
      dst[mt][ks] = s_;                                                  \
    }

// per-batch arrive/wait (canonical multi-block barrier, device scope)
__device__ __forceinline__ void arrive_wait(unsigned* ctr) {
  __syncthreads();   // all threads' prior mem ops drained (vmcnt 0 at barrier)
  if (threadIdx.x == 0) {
    __hip_atomic_fetch_add(ctr, 1u, __ATOMIC_RELEASE, __HIP_MEMORY_SCOPE_AGENT);
    while (__hip_atomic_load(ctr, __ATOMIC_ACQUIRE, __HIP_MEMORY_SCOPE_AGENT) <
           (unsigned)NSTRIP)
      __builtin_amdgcn_s_sleep(8);
  }
  __syncthreads();
  __threadfence();   // belt-and-braces agent-scope acquire for all threads
}

// ---------------------------------------------------------------- fused kernel
__global__ __launch_bounds__(256, 2) void k_fused(
    const float* __restrict__ x, const float* __restrict__ Wq,
    const float* __restrict__ Wk, const float* __restrict__ Wv,
    const float* __restrict__ Wo, const float* __restrict__ bo,
    const float* __restrict__ gnw, const float* __restrict__ gnb,
    float* __restrict__ ctx_u, float* __restrict__ Zsum,
    float* __restrict__ stats, unsigned* __restrict__ done1,
    unsigned* __restrict__ done2, float* __restrict__ outp) {
  __shared__ char smem[53248];           // 52 KB union across phases
  short* frag  = (short*)smem;           // 16384 B (phase 1 & 2)
  short* ekbuf = (short*)(smem + 16384); // 18432 B (phase 1)
  short* vbuf  = (short*)(smem + 34816); // 18432 B (phase 1)
  short* qat   = (short*)(smem + 16384); // 17408 B (phase 2)
  short* ctxT  = (short*)(smem + 33792); // 10240 B (phase 2)

  const int tid = threadIdx.x;
  const int w = tid >> 6, L = tid & 63, l15 = tid & 15, q4 = (tid & 63) >> 4;
  const int b = blockIdx.x / NSTRIP;
  const int strip = blockIdx.x % NSTRIP;
  const float* xw = x + (size_t)b * (C_ * N_) + (size_t)(w * 32 + q4 * 8) * N_
                      + (size_t)(strip * TPB) * NB + l15;
  const floatx4 z4 = {0.f, 0.f, 0.f, 0.f};
  float xr[4][8];

  // ================================================== phase 1: k,v proj + ctx/Z
  {
    short8 ak[2][4], av[2][4];
    WFRAG(ak, Wk, C_)
    WFRAG(av, Wv, C_)

    floatx4 ca[2][2] = {{z4, z4}, {z4, z4}};
    float zreg[2][4] = {{0.f,0.f,0.f,0.f},{0.f,0.f,0.f,0.f}};

    XLOAD(0)
    XCVT(frag)
    XLOAD(1)

    for (int t = 0; t < TPB; ++t) {
      __syncthreads();   // b1: frag(t) visible

      // k GEMM (acck live only until pack-ek)
      floatx4 acck[2][4];
#pragma unroll
      for (int mt = 0; mt < 2; ++mt)
#pragma unroll
        for (int nt = 0; nt < 4; ++nt) acck[mt][nt] = z4;
#pragma unroll
      for (int ks = 0; ks < 4; ++ks) {
        short8 Bf[4];
#pragma unroll
        for (int nt = 0; nt < 4; ++nt)
          Bf[nt] = *(const short8*)&frag[((ks * 4 + nt) * 64 + L) * 8];
#pragma unroll
        for (int mt = 0; mt < 2; ++mt)
#pragma unroll
          for (int nt = 0; nt < 4; ++nt)
            acck[mt][nt] = __builtin_amdgcn_mfma_f32_16x16x32_bf16(ak[mt][ks], Bf[nt], acck[mt][nt], 0, 0, 0);
      }

      // exp(k) + Z + pack ek (kills acck)
#pragma unroll
      for (int mt = 0; mt < 2; ++mt)
#pragma unroll
        for (int nt = 0; nt < 4; ++nt)
#pragma unroll
          for (int r = 0; r < 4; ++r)
            acck[mt][nt][r] = __expf(acck[mt][nt][r]);
#pragma unroll
      for (int mt = 0; mt < 2; ++mt)
#pragma unroll
        for (int r = 0; r < 4; ++r)
          zreg[mt][r] += acck[mt][0][r] + acck[mt][1][r] + acck[mt][2][r] + acck[mt][3][r];
#pragma unroll
      for (int mt = 0; mt < 2; ++mt)
#pragma unroll
        for (int nt = 0; nt < 4; ++nt)
#pragma unroll
          for (int r = 0; r < 4; ++r)
            ekbuf[(w * 32 + mt * 16 + q4 * 4 + r) * STV + nt * 16 + l15] = f2bf(acck[mt][nt][r]);

      // v GEMM (accv born after acck dead)
      floatx4 accv[2][4];
#pragma unroll
      for (int mt = 0; mt < 2; ++mt)
#pragma unroll
        for (int nt = 0; nt < 4; ++nt) accv[mt][nt] = z4;
#pragma unroll
      for (int ks = 0; ks < 4; ++ks) {
        short8 Bf[4];
#pragma unroll
        for (int nt = 0; nt < 4; ++nt)
          Bf[nt] = *(const short8*)&frag[((ks * 4 + nt) * 64 + L) * 8];
#pragma unroll
        for (int mt = 0; mt < 2; ++mt)
#pragma unroll
          for (int nt = 0; nt < 4; ++nt)
            accv[mt][nt] = __builtin_amdgcn_mfma_f32_16x16x32_bf16(av[mt][ks], Bf[nt], accv[mt][nt], 0, 0, 0);
      }
      __syncthreads();   // b2: frag reads done -> rewrite allowed

      if (t + 1 < TPB) {
        XCVT(frag)
        if (t + 2 < TPB) { XLOAD(t + 2) }
      }

      // pack v (wave-local rows)
#pragma unroll
      for (int mt = 0; mt < 2; ++mt)
#pragma unroll
        for (int nt = 0; nt < 4; ++nt)
#pragma unroll
          for (int r = 0; r < 4; ++r)
            vbuf[(w * 32 + mt * 16 + q4 * 4 + r) * STV + nt * 16 + l15] = f2bf(accv[mt][nt][r]);

      // ctx partial via MFMA (wave-local rows)
#pragma unroll
      for (int ks = 0; ks < 2; ++ks) {
        short8 ae[2], be[2];
#pragma unroll
        for (int mt = 0; mt < 2; ++mt)
          ae[mt] = *(const short8*)&ekbuf[(w * 32 + mt * 16 + l15) * STV + ks * 32 + q4 * 8];
#pragma unroll
        for (int nt = 0; nt < 2; ++nt)
          be[nt] = *(const short8*)&vbuf[(w * 32 + nt * 16 + l15) * STV + ks * 32 + q4 * 8];
#pragma unroll
        for (int mt = 0; mt < 2; ++mt)
#pragma unroll
          for (int nt = 0; nt < 2; ++nt)
            ca[mt][nt] = __builtin_amdgcn_mfma_f32_16x16x32_bf16(ae[mt], be[nt], ca[mt][nt], 0, 0, 0);
      }
    }

    // Z: reduce over l15, one atomic per row
#pragma unroll
    for (int mt = 0; mt < 2; ++mt)
#pragma unroll
      for (int r = 0; r < 4; ++r) {
        float s = zreg[mt][r];
        s += __shfl_xor(s, 1); s += __shfl_xor(s, 2);
        s += __shfl_xor(s, 4); s += __shfl_xor(s, 8);
        if (l15 == 0) atomicAdd(&Zsum[b * HID + w * 32 + mt * 16 + q4 * 4 + r], s);
      }

    // ctx atomics (once per block)
    float* cb = &ctx_u[((size_t)b * H_ + w) * (D_ * D_)];
#pragma unroll
    for (int mt = 0; mt < 2; ++mt)
#pragma unroll
      for (int nt = 0; nt < 2; ++nt)
#pragma unroll
        for (int r = 0; r < 4; ++r)
          atomicAdd(&cb[(mt * 16 + q4 * 4 + r) * D_ + nt * 16 + l15], ca[mt][nt][r]);
  }

  // wait: batch b's ctx/Z complete
  arrive_wait(&done1[b]);

  // ================================================== phase 2: q proj + attn + Wo + stats
  float s1 = 0.f, s2 = 0.f;
  {
    XLOAD(0)
    XCVT(frag)
    XLOAD(1)
#pragma unroll
    for (int i = 0; i < 16; ++i) {
      const int idx = tid + i * 256;               // h*1024 + d*32 + e
      float v = ctx_u[(size_t)b * (H_ * D_ * D_) + idx] *
                __builtin_amdgcn_rcpf(Zsum[b * HID + (idx >> 5)]);
      ctxT[((idx >> 10) * 32 + (idx & 31)) * SCT + ((idx >> 5) & 31)] = f2bf(v);
    }

    short8 aq[2][4], ao[2][4];
    WFRAG(aq, Wq, C_)
    WFRAG(ao, Wo, HID)

    for (int t = 0; t < TPB; ++t) {
      const int n0 = (strip * TPB + t) * NB;
      __syncthreads();   // b1: frag(t) + (t==0) ctxT visible

      floatx4 acc[2][4];
#pragma unroll
      for (int mt = 0; mt < 2; ++mt)
#pragma unroll
        for (int nt = 0; nt < 4; ++nt) acc[mt][nt] = z4;
#pragma unroll
      for (int ks = 0; ks < 4; ++ks) {
        short8 Bf[4];
#pragma unroll
        for (int nt = 0; nt < 4; ++nt)
          Bf[nt] = *(const short8*)&frag[((ks * 4 + nt) * 64 + L) * 8];
#pragma unroll
        for (int mt = 0; mt < 2; ++mt)
#pragma unroll
          for (int nt = 0; nt < 4; ++nt)
            acc[mt][nt] = __builtin_amdgcn_mfma_f32_16x16x32_bf16(aq[mt][ks], Bf[nt], acc[mt][nt], 0, 0, 0);
      }
      __syncthreads();   // b2: frag reads done -> rewrite allowed

      if (t + 1 < TPB) {
        XCVT(frag)
        if (t + 2 < TPB) { XLOAD(t + 2) }
      }

      // exp(q); per-column softmax denom via shuffle
#pragma unroll
      for (int mt = 0; mt < 2; ++mt)
#pragma unroll
        for (int nt = 0; nt < 4; ++nt)
#pragma unroll
          for (int r = 0; r < 4; ++r)
            acc[mt][nt][r] = __expf(acc[mt][nt][r]);
      float inv[4];
#pragma unroll
      for (int nt = 0; nt < 4; ++nt) {
        float s = 0.f;
#pragma unroll
        for (int mt = 0; mt < 2; ++mt)
#pragma unroll
          for (int r = 0; r < 4; ++r) s += acc[mt][nt][r];
        s += __shfl_xor(s, 16); s += __shfl_xor(s, 32);
        inv[nt] = SCALE * __builtin_amdgcn_rcpf(s);
      }

      // scaled eq^T into qat (wave-local columns)
#pragma unroll
      for (int mt = 0; mt < 2; ++mt)
#pragma unroll
        for (int nt = 0; nt < 4; ++nt) {
          short4v pk = { f2bf(acc[mt][nt][0] * inv[nt]), f2bf(acc[mt][nt][1] * inv[nt]),
                         f2bf(acc[mt][nt][2] * inv[nt]), f2bf(acc[mt][nt][3] * inv[nt]) };
          *(short4v*)&qat[(nt * 16 + l15) * STA + w * 32 + mt * 16 + q4 * 4] = pk;
        }

      // attn: out[e][n] = sum_d ctxT[e][d] * eq[d][n]   (wave-local)
      {
        floatx4 aacc[2][4];
#pragma unroll
        for (int mt = 0; mt < 2; ++mt)
#pragma unroll
          for (int nt = 0; nt < 4; ++nt) aacc[mt][nt] = z4;
        short8 ae[2];
#pragma unroll
        for (int mt = 0; mt < 2; ++mt)
          ae[mt] = *(const short8*)&ctxT[(w * 32 + mt * 16 + l15) * SCT + q4 * 8];
#pragma unroll
        for (int nt = 0; nt < 4; ++nt) {
          short8 bq = *(const short8*)&qat[(nt * 16 + l15) * STA + w * 32 + q4 * 8];
#pragma unroll
          for (int mt = 0; mt < 2; ++mt)
            aacc[mt][nt] = __builtin_amdgcn_mfma_f32_16x16x32_bf16(ae[mt], bq, aacc[mt][nt], 0, 0, 0);
        }
#pragma unroll
        for (int nt = 0; nt < 4; ++nt)
#pragma unroll
          for (int mt = 0; mt < 2; ++mt) {
            short4v pk = { f2bf(aacc[mt][nt][0]), f2bf(aacc[mt][nt][1]),
                           f2bf(aacc[mt][nt][2]), f2bf(aacc[mt][nt][3]) };
            *(short4v*)&qat[(nt * 16 + l15) * STA + w * 32 + mt * 16 + q4 * 4] = pk;
          }
      }
      __syncthreads();   // b3: attn^T visible to all waves

      // out_pre = Wo @ attn + bo
      floatx4 oacc[2][4];
#pragma unroll
      for (int mt = 0; mt < 2; ++mt)
#pragma unroll
        for (int nt = 0; nt < 4; ++nt) oacc[mt][nt] = z4;
#pragma unroll
      for (int ks = 0; ks < 4; ++ks) {
        short8 bf8[4];
#pragma unroll
        for (int nt = 0; nt < 4; ++nt)
          bf8[nt] = *(const short8*)&qat[(nt * 16 + l15) * STA + ks * 32 + q4 * 8];
#pragma unroll
        for (int mt = 0; mt < 2; ++mt)
#pragma unroll
          for (int nt = 0; nt < 4; ++nt)
            oacc[mt][nt] = __builtin_amdgcn_mfma_f32_16x16x32_bf16(ao[mt][ks], bf8[nt], oacc[mt][nt], 0, 0, 0);
      }

      // epilogue: +bo, store, accumulate stats in registers
#pragma unroll
      for (int mt = 0; mt < 2; ++mt) {
        const int rowbase = w * 32 + mt * 16 + q4 * 4;
        const floatx4 bo4 = *(const floatx4*)&bo[rowbase];
#pragma unroll
        for (int nt = 0; nt < 4; ++nt) {
          const int n = n0 + nt * 16 + l15;
#pragma unroll
          for (int r = 0; r < 4; ++r) {
            float vv = oacc[mt][nt][r] + bo4[r];
            outp[(size_t)b * (C_ * N_) + (size_t)(rowbase + r) * N_ + n] = vv;
            s1 += vv; s2 += vv * vv;
          }
        }
      }
    }

    // stats: wave reduce + one atomic pair per wave
#pragma unroll
    for (int m = 1; m < 64; m <<= 1) {
      s1 += __shfl_xor(s1, m);
      s2 += __shfl_xor(s2, m);
    }
    if ((tid & 63) == 0) {
      atomicAdd(&stats[b * 2 + 0], s1);
      atomicAdd(&stats[b * 2 + 1], s2);
    }
  }

  // wait: batch b's stats complete
  arrive_wait(&done2[b]);

  // ================================================== phase 3: GroupNorm (own region, L2-hot)
  {
    const float M = (float)(C_ * N_);
    const float mu = stats[b * 2 + 0] / M;
    const float var = stats[b * 2 + 1] / M - mu * mu;
    const float rs = rsqrtf(var + EPS);
    float* pb = outp + (size_t)b * (C_ * N_) + (size_t)(strip * TPB) * NB;
#pragma unroll
    for (int i = 0; i < 32; ++i) {
      const int f = tid + i * 256;        // 0..8191: row = f>>6, col4 = f&63
      const int row = f >> 6, c4 = f & 63;
      const float wgt = gnw[row] * rs;
      const float bia = gnb[row] - mu * wgt;
      floatx4* p = (floatx4*)(pb + (size_t)row * N_) + c4;
      floatx4 v = *p;
      v[0] = v[0] * wgt + bia;
      v[1] = v[1] * wgt + bia;
      v[2] = v[2] * wgt + bia;
      v[3] = v[3] * wgt + bia;
      *p = v;
    }
  }
}

// ---------------------------------------------------------------- launch
extern "C" void kernel_launch(void* const* d_in, const int* in_sizes, int n_in,
                              void* d_out, int out_size, void* d_ws, size_t ws_size,
                              hipStream_t stream) {
  (void)in_sizes; (void)n_in; (void)out_size; (void)ws_size;
  const float* x   = (const float*)d_in[0];
  const float* Wq  = (const float*)d_in[1];
  const float* Wk  = (const float*)d_in[2];
  const float* Wv  = (const float*)d_in[3];
  const float* Wo  = (const float*)d_in[4];
  const float* bo  = (const float*)d_in[5];
  const float* gnw = (const float*)d_in[6];
  const float* gnb = (const float*)d_in[7];
  float* outp  = (float*)d_out;
  float* ctx_u = (float*)d_ws;                        // 131072 f
  float* Zsum  = ctx_u + B_ * H_ * D_ * D_;           // 4096 f
  float* stats = Zsum + B_ * HID;                     // 64 f
  unsigned* done1 = (unsigned*)(stats + B_ * 2);      // 32 u32
  unsigned* done2 = done1 + B_;                       // 32 u32
  const size_t zbytes = (size_t)(B_ * H_ * D_ * D_ + B_ * HID + B_ * 2) * sizeof(float)
                      + (size_t)(2 * B_) * sizeof(unsigned);
  hipMemsetAsync(d_ws, 0, zbytes, stream);
  hipLaunchKernelGGL(k_fused, dim3(B_ * NSTRIP), dim3(256), 0, stream,
                     x, Wq, Wk, Wv, Wo, bo, gnw, gnb,
                     ctx_u, Zsum, stats, done1, done2, outp);
}

// Round 6
// 285.778 us; speedup vs baseline: 1.3749x; 1.3749x over previous
//
#include <hip/hip_runtime.h>

// LinearAttention fused pipeline for MI355X (gfx950) — round 10.
// Post-mortem r9: whole-pipeline fusion spilled (union of phase register
// demands; WRITE 188 MB = +60 MB scratch) and the slow phases were amplified
// by 16-block barriers -> 325 us. r10 shrinks fusion scope to the proven
// pieces: (a) k_wcast deleted — weights converted f32->bf16 in registers
// (r9-proven bit-identical); (b) GroupNorm fused into K2 as phase 3 behind
// ONE per-batch arrive/wait — each block renorms the 128 KB region it just
// wrote (XCD-L2 hot, no HBM re-read), killing the gnorm dispatch + gap;
// (c) K1 and K2 remain SEPARATE kernels so each keeps r8's no-spill
// register footprint. 3 dispatches total (memset + K1 + K2GN).
//
// ws: ctx_u[32][4][32][32] f32 | Z[32][128] f32 | stats[32][2] f32 | done[32] u32

#define B_   32
#define C_   128
#define N_   4096
#define H_   4
#define D_   32
#define HID  128
#define NB   64
#define TPB  4        // n-tiles per block
#define NSTRIP 16     // strips per batch (NSTRIP*TPB*NB == N_)
#define STV  72       // ek/v row stride (shorts)
#define STA  136      // eqT/attnT row stride (shorts)
#define SCT  40       // ctxT row stride (shorts)
#define SCALE 0.1767766952966369f
#define EPS  1e-5f

typedef __attribute__((ext_vector_type(8))) short short8;
typedef __attribute__((ext_vector_type(4))) short short4v;
typedef __attribute__((ext_vector_type(4))) float floatx4;

__device__ __forceinline__ short f2bf(float f) {   // RNE fp32 -> bf16
  unsigned u = __float_as_uint(f);
  u += 0x7FFFu + ((u >> 16) & 1u);
  return (short)(u >> 16);
}

// load the wave's c-quarter of x tile tt into registers (32 scalar f32,
// each instr coalesces 4 rows x 64B across the wave)
#define XLOAD(tt)                                                        \
  _Pragma("unroll")                                                      \
  for (int nt = 0; nt < 4; ++nt)                                         \
    _Pragma("unroll")                                                    \
    for (int j = 0; j < 8; ++j)                                          \
      xr[nt][j] = xw[(size_t)j * N_ + (size_t)(tt) * NB + nt * 16];

// convert + write this wave's 4 fragments (lane-linear b128, conflict-free)
#define XCVT(fragbuf)                                                    \
  _Pragma("unroll")                                                      \
  for (int nt = 0; nt < 4; ++nt) {                                       \
    short8 s;                                                            \
    _Pragma("unroll")                                                    \
    for (int j = 0; j < 8; ++j) s[j] = f2bf(xr[nt][j]);                  \
    *(short8*)&fragbuf[((w * 4 + nt) * 64 + L) * 8] = s;                 \
  }

// convert a weight matrix's A-frags f32 -> bf16 in registers (bit-identical
// to the old k_wcast path: same RNE f2bf on the same values)
#define WFRAG(dst, Wsrc, LD)                                             \
  _Pragma("unroll")                                                      \
  for (int mt = 0; mt < 2; ++mt)                                         \
    _Pragma("unroll")                                                    \
    for (int ks = 0; ks < 4; ++ks) {                                     \
      const float* p_ = &Wsrc[(w * 32 + mt * 16 + l15) * LD + ks * 32 + q4 * 8]; \
      floatx4 a0_ = *(const floatx4*)p_;                                 \
      floatx4 a1_ = *(const floatx4*)(p_ + 4);                           \
      short8 s_;                                                         \
      s_[0] = f2bf(a0_[0]); s_[1] = f2bf(a0_[1]);                        \
      s_[2] = f2bf(a0_[2]); s_[3] = f2bf(a0_[3]);                        \
      s_[4] = f2bf(a1_[0]); s_[5] = f2bf(a1_[1]);                        \
      s_[6] = f2bf(a1_[2]); s_[7] = f2bf(a1_[3]);                        \
      dst[mt][ks] = s_;                                                  \
    }

// ---------------------------------------------------------------- K1: k,v proj + ctx/Z
__global__ __launch_bounds__(256, 2) void k_kv_ctx(
    const float* __restrict__ x, const float* __restrict__ Wk,
    const float* __restrict__ Wv, float* __restrict__ ctx_u,
    float* __restrict__ Zsum) {
  __shared__ short frag[8192];           // 16 KB bf16 fragment tile
  __shared__ short ekbuf[C_ * STV];      // 18 KB
  __shared__ short vbuf [C_ * STV];      // 18 KB
  const int tid = threadIdx.x;
  const int w = tid >> 6, L = tid & 63, l15 = tid & 15, q4 = (tid & 63) >> 4;
  const int b = blockIdx.x / NSTRIP;
  const int strip = blockIdx.x % NSTRIP;
  const float* xw = x + (size_t)b * (C_ * N_) + (size_t)(w * 32 + q4 * 8) * N_
                      + (size_t)(strip * TPB) * NB + l15;

  short8 ak[2][4], av[2][4];
  WFRAG(ak, Wk, C_)
  WFRAG(av, Wv, C_)

  const floatx4 z4 = {0.f, 0.f, 0.f, 0.f};
  floatx4 ca[2][2] = {{z4, z4}, {z4, z4}};   // ctx accumulator across tiles
  float zreg[2][4] = {{0.f,0.f,0.f,0.f},{0.f,0.f,0.f,0.f}};
  float xr[4][8];

  // prologue: tile0 -> regs -> frag; issue tile1 loads
  XLOAD(0)
  XCVT(frag)
  XLOAD(1)

  for (int t = 0; t < TPB; ++t) {
    __syncthreads();   // b1: frag(t) visible

    // ---- k GEMM (acck live only until pack-ek below)
    floatx4 acck[2][4];
#pragma unroll
    for (int mt = 0; mt < 2; ++mt)
#pragma unroll
      for (int nt = 0; nt < 4; ++nt) acck[mt][nt] = z4;
#pragma unroll
    for (int ks = 0; ks < 4; ++ks) {
      short8 Bf[4];
#pragma unroll
      for (int nt = 0; nt < 4; ++nt)
        Bf[nt] = *(const short8*)&frag[((ks * 4 + nt) * 64 + L) * 8];
#pragma unroll
      for (int mt = 0; mt < 2; ++mt)
#pragma unroll
        for (int nt = 0; nt < 4; ++nt)
          acck[mt][nt] = __builtin_amdgcn_mfma_f32_16x16x32_bf16(ak[mt][ks], Bf[nt], acck[mt][nt], 0, 0, 0);
    }

    // exp(k) + Z partial accumulation + pack ek (kills acck)
#pragma unroll
    for (int mt = 0; mt < 2; ++mt)
#pragma unroll
      for (int nt = 0; nt < 4; ++nt)
#pragma unroll
        for (int r = 0; r < 4; ++r)
          acck[mt][nt][r] = __expf(acck[mt][nt][r]);
#pragma unroll
    for (int mt = 0; mt < 2; ++mt)
#pragma unroll
      for (int r = 0; r < 4; ++r)
        zreg[mt][r] += acck[mt][0][r] + acck[mt][1][r] + acck[mt][2][r] + acck[mt][3][r];
#pragma unroll
    for (int mt = 0; mt < 2; ++mt)
#pragma unroll
      for (int nt = 0; nt < 4; ++nt)
#pragma unroll
        for (int r = 0; r < 4; ++r)
          ekbuf[(w * 32 + mt * 16 + q4 * 4 + r) * STV + nt * 16 + l15] = f2bf(acck[mt][nt][r]);

    // ---- v GEMM (accv born after acck dead; re-reads frag, conflict-free)
    floatx4 accv[2][4];
#pragma unroll
    for (int mt = 0; mt < 2; ++mt)
#pragma unroll
      for (int nt = 0; nt < 4; ++nt) accv[mt][nt] = z4;
#pragma unroll
    for (int ks = 0; ks < 4; ++ks) {
      short8 Bf[4];
#pragma unroll
      for (int nt = 0; nt < 4; ++nt)
        Bf[nt] = *(const short8*)&frag[((ks * 4 + nt) * 64 + L) * 8];
#pragma unroll
      for (int mt = 0; mt < 2; ++mt)
#pragma unroll
        for (int nt = 0; nt < 4; ++nt)
          accv[mt][nt] = __builtin_amdgcn_mfma_f32_16x16x32_bf16(av[mt][ks], Bf[nt], accv[mt][nt], 0, 0, 0);
    }
    __syncthreads();   // b2: all frag reads done -> rewrite allowed

    // convert regs (tile t+1) -> frag; issue loads for tile t+2
    if (t + 1 < TPB) {
      XCVT(frag)
      if (t + 2 < TPB) { XLOAD(t + 2) }
    }

    // pack v (wave-local rows, in-wave DS ordering)
#pragma unroll
    for (int mt = 0; mt < 2; ++mt)
#pragma unroll
      for (int nt = 0; nt < 4; ++nt)
#pragma unroll
        for (int r = 0; r < 4; ++r)
          vbuf[(w * 32 + mt * 16 + q4 * 4 + r) * STV + nt * 16 + l15] = f2bf(accv[mt][nt][r]);

    // ctx partial via MFMA (wave-local rows), accumulates across tiles
#pragma unroll
    for (int ks = 0; ks < 2; ++ks) {
      short8 ae[2], be[2];
#pragma unroll
      for (int mt = 0; mt < 2; ++mt)
        ae[mt] = *(const short8*)&ekbuf[(w * 32 + mt * 16 + l15) * STV + ks * 32 + q4 * 8];
#pragma unroll
      for (int nt = 0; nt < 2; ++nt)
        be[nt] = *(const short8*)&vbuf[(w * 32 + nt * 16 + l15) * STV + ks * 32 + q4 * 8];
#pragma unroll
      for (int mt = 0; mt < 2; ++mt)
#pragma unroll
        for (int nt = 0; nt < 2; ++nt)
          ca[mt][nt] = __builtin_amdgcn_mfma_f32_16x16x32_bf16(ae[mt], be[nt], ca[mt][nt], 0, 0, 0);
    }
  }

  // Z: reduce over l15, one atomic per row
#pragma unroll
  for (int mt = 0; mt < 2; ++mt)
#pragma unroll
    for (int r = 0; r < 4; ++r) {
      float s = zreg[mt][r];
      s += __shfl_xor(s, 1); s += __shfl_xor(s, 2);
      s += __shfl_xor(s, 4); s += __shfl_xor(s, 8);
      if (l15 == 0) atomicAdd(&Zsum[b * HID + w * 32 + mt * 16 + q4 * 4 + r], s);
    }

  // ctx atomics (once per block)
  float* cb = &ctx_u[((size_t)b * H_ + w) * (D_ * D_)];
#pragma unroll
  for (int mt = 0; mt < 2; ++mt)
#pragma unroll
    for (int nt = 0; nt < 2; ++nt)
#pragma unroll
      for (int r = 0; r < 4; ++r)
        atomicAdd(&cb[(mt * 16 + q4 * 4 + r) * D_ + nt * 16 + l15], ca[mt][nt][r]);
}

// ---------------------------------------------------------------- K2: q proj + attn + Wo + stats + GroupNorm
__global__ __launch_bounds__(256, 2) void k_q_attn_o(
    const float* __restrict__ x, const float* __restrict__ Wq,
    const float* __restrict__ Wo, const float* __restrict__ bo,
    const float* __restrict__ gnw, const float* __restrict__ gnb,
    const float* __restrict__ ctx_u, const float* __restrict__ Zsum,
    float* __restrict__ stats, unsigned* __restrict__ done,
    float* __restrict__ outp) {
  __shared__ short frag[8192];        // 16 KB bf16 fragment tile
  __shared__ short qat[NB * STA];     // eq^T then attn^T, 17 KB
  __shared__ short ctxT[HID * SCT];   // 10 KB
  const int tid = threadIdx.x;
  const int w = tid >> 6, L = tid & 63, l15 = tid & 15, q4 = (tid & 63) >> 4;
  const int b = blockIdx.x / NSTRIP;
  const int strip = blockIdx.x % NSTRIP;
  const float* xw = x + (size_t)b * (C_ * N_) + (size_t)(w * 32 + q4 * 8) * N_
                      + (size_t)(strip * TPB) * NB + l15;

  // prologue: tile0 -> regs -> frag; issue tile1 loads; ctxT fill overlaps
  float xr[4][8];
  XLOAD(0)
  XCVT(frag)
  XLOAD(1)
#pragma unroll
  for (int i = 0; i < 16; ++i) {
    const int idx = tid + i * 256;               // h*1024 + d*32 + e
    float v = ctx_u[(size_t)b * (H_ * D_ * D_) + idx] *
              __builtin_amdgcn_rcpf(Zsum[b * HID + (idx >> 5)]);
    ctxT[((idx >> 10) * 32 + (idx & 31)) * SCT + ((idx >> 5) & 31)] = f2bf(v);
  }

  short8 aq[2][4], ao[2][4];
  WFRAG(aq, Wq, C_)
  WFRAG(ao, Wo, HID)

  const floatx4 z4 = {0.f, 0.f, 0.f, 0.f};
  float s1 = 0.f, s2 = 0.f;

  for (int t = 0; t < TPB; ++t) {
    const int n0 = (strip * TPB + t) * NB;
    __syncthreads();   // b1: frag(t) + (t==0) ctxT visible

    // q = Wq @ x — B-frags are lane-linear ds_read_b128, no converts
    floatx4 acc[2][4];
#pragma unroll
    for (int mt = 0; mt < 2; ++mt)
#pragma unroll
      for (int nt = 0; nt < 4; ++nt) acc[mt][nt] = z4;
#pragma unroll
    for (int ks = 0; ks < 4; ++ks) {
      short8 Bf[4];
#pragma unroll
      for (int nt = 0; nt < 4; ++nt)
        Bf[nt] = *(const short8*)&frag[((ks * 4 + nt) * 64 + L) * 8];
#pragma unroll
      for (int mt = 0; mt < 2; ++mt)
#pragma unroll
        for (int nt = 0; nt < 4; ++nt)
          acc[mt][nt] = __builtin_amdgcn_mfma_f32_16x16x32_bf16(aq[mt][ks], Bf[nt], acc[mt][nt], 0, 0, 0);
    }
    __syncthreads();   // b2: frag reads done -> rewrite allowed

    // convert regs (tile t+1) -> frag; issue loads for tile t+2
    if (t + 1 < TPB) {
      XCVT(frag)
      if (t + 2 < TPB) { XLOAD(t + 2) }
    }

    // exp(q); per-column softmax denom via shuffle
#pragma unroll
    for (int mt = 0; mt < 2; ++mt)
#pragma unroll
      for (int nt = 0; nt < 4; ++nt)
#pragma unroll
        for (int r = 0; r < 4; ++r)
          acc[mt][nt][r] = __expf(acc[mt][nt][r]);
    float inv[4];
#pragma unroll
    for (int nt = 0; nt < 4; ++nt) {
      float s = 0.f;
#pragma unroll
      for (int mt = 0; mt < 2; ++mt)
#pragma unroll
        for (int r = 0; r < 4; ++r) s += acc[mt][nt][r];
      s += __shfl_xor(s, 16); s += __shfl_xor(s, 32);
      inv[nt] = SCALE * __builtin_amdgcn_rcpf(s);
    }

    // scaled eq^T into qat (wave-local columns)
#pragma unroll
    for (int mt = 0; mt < 2; ++mt)
#pragma unroll
      for (int nt = 0; nt < 4; ++nt) {
        short4v pk = { f2bf(acc[mt][nt][0] * inv[nt]), f2bf(acc[mt][nt][1] * inv[nt]),
                       f2bf(acc[mt][nt][2] * inv[nt]), f2bf(acc[mt][nt][3] * inv[nt]) };
        *(short4v*)&qat[(nt * 16 + l15) * STA + w * 32 + mt * 16 + q4 * 4] = pk;
      }

    // attn: out[e][n] = sum_d ctxT[e][d] * eq[d][n]   (wave-local)
    {
      floatx4 aacc[2][4];
#pragma unroll
      for (int mt = 0; mt < 2; ++mt)
#pragma unroll
        for (int nt = 0; nt < 4; ++nt) aacc[mt][nt] = z4;
      short8 ae[2];
#pragma unroll
      for (int mt = 0; mt < 2; ++mt)
        ae[mt] = *(const short8*)&ctxT[(w * 32 + mt * 16 + l15) * SCT + q4 * 8];
#pragma unroll
      for (int nt = 0; nt < 4; ++nt) {
        short8 bq = *(const short8*)&qat[(nt * 16 + l15) * STA + w * 32 + q4 * 8];
#pragma unroll
        for (int mt = 0; mt < 2; ++mt)
          aacc[mt][nt] = __builtin_amdgcn_mfma_f32_16x16x32_bf16(ae[mt], bq, aacc[mt][nt], 0, 0, 0);
      }
      // attn^T over eq^T (same wave-local columns)
#pragma unroll
      for (int nt = 0; nt < 4; ++nt)
#pragma unroll
        for (int mt = 0; mt < 2; ++mt) {
          short4v pk = { f2bf(aacc[mt][nt][0]), f2bf(aacc[mt][nt][1]),
                         f2bf(aacc[mt][nt][2]), f2bf(aacc[mt][nt][3]) };
          *(short4v*)&qat[(nt * 16 + l15) * STA + w * 32 + mt * 16 + q4 * 4] = pk;
        }
    }
    __syncthreads();   // b3: attn^T visible to all waves

    // out_pre = Wo @ attn + bo
    floatx4 oacc[2][4];
#pragma unroll
    for (int mt = 0; mt < 2; ++mt)
#pragma unroll
      for (int nt = 0; nt < 4; ++nt) oacc[mt][nt] = z4;
#pragma unroll
    for (int ks = 0; ks < 4; ++ks) {
      short8 bf8[4];
#pragma unroll
      for (int nt = 0; nt < 4; ++nt)
        bf8[nt] = *(const short8*)&qat[(nt * 16 + l15) * STA + ks * 32 + q4 * 8];
#pragma unroll
      for (int mt = 0; mt < 2; ++mt)
#pragma unroll
        for (int nt = 0; nt < 4; ++nt)
          oacc[mt][nt] = __builtin_amdgcn_mfma_f32_16x16x32_bf16(ao[mt][ks], bf8[nt], oacc[mt][nt], 0, 0, 0);
    }

    // epilogue: +bo, store pre-norm, accumulate stats in registers
#pragma unroll
    for (int mt = 0; mt < 2; ++mt) {
      const int rowbase = w * 32 + mt * 16 + q4 * 4;
      const floatx4 bo4 = *(const floatx4*)&bo[rowbase];
#pragma unroll
      for (int nt = 0; nt < 4; ++nt) {
        const int n = n0 + nt * 16 + l15;
#pragma unroll
        for (int r = 0; r < 4; ++r) {
          float vv = oacc[mt][nt][r] + bo4[r];
          outp[(size_t)b * (C_ * N_) + (size_t)(rowbase + r) * N_ + n] = vv;
          s1 += vv; s2 += vv * vv;
        }
      }
    }
  }

  // stats: wave reduce + one atomic pair per wave
#pragma unroll
  for (int m = 1; m < 64; m <<= 1) {
    s1 += __shfl_xor(s1, m);
    s2 += __shfl_xor(s2, m);
  }
  if ((tid & 63) == 0) {
    atomicAdd(&stats[b * 2 + 0], s1);
    atomicAdd(&stats[b * 2 + 1], s2);
  }

  // -------- per-batch arrive/wait on stats (16 peer blocks)
  __syncthreads();                      // all waves' atomics issued+drained
  if (tid == 0) {
    __hip_atomic_fetch_add(&done[b], 1u, __ATOMIC_RELEASE, __HIP_MEMORY_SCOPE_AGENT);
    while (__hip_atomic_load(&done[b], __ATOMIC_ACQUIRE, __HIP_MEMORY_SCOPE_AGENT) <
           (unsigned)NSTRIP)
      __builtin_amdgcn_s_sleep(8);
  }
  __syncthreads();
  __threadfence();                      // agent-scope acquire for all threads

  // -------- phase 3: GroupNorm over this block's own strip (L2-hot)
  {
    const float M = (float)(C_ * N_);
    const float mu = stats[b * 2 + 0] / M;
    const float var = stats[b * 2 + 1] / M - mu * mu;
    const float rs = rsqrtf(var + EPS);
    float* pb = outp + (size_t)b * (C_ * N_) + (size_t)(strip * TPB) * NB;
#pragma unroll
    for (int i = 0; i < 32; ++i) {
      const int f = tid + i * 256;        // 0..8191: row = f>>6, col4 = f&63
      const int row = f >> 6, c4 = f & 63;
      const float wgt = gnw[row] * rs;
      const float bia = gnb[row] - mu * wgt;
      floatx4* p = (floatx4*)(pb + (size_t)row * N_) + c4;
      floatx4 v = *p;
      v[0] = v[0] * wgt + bia;
      v[1] = v[1] * wgt + bia;
      v[2] = v[2] * wgt + bia;
      v[3] = v[3] * wgt + bia;
      *p = v;
    }
  }
}

// ---------------------------------------------------------------- launch
extern "C" void kernel_launch(void* const* d_in, const int* in_sizes, int n_in,
                              void* d_out, int out_size, void* d_ws, size_t ws_size,
                              hipStream_t stream) {
  (void)in_sizes; (void)n_in; (void)out_size; (void)ws_size;
  const float* x   = (const float*)d_in[0];
  const float* Wq  = (const float*)d_in[1];
  const float* Wk  = (const float*)d_in[2];
  const float* Wv  = (const float*)d_in[3];
  const float* Wo  = (const float*)d_in[4];
  const float* bo  = (const float*)d_in[5];
  const float* gnw = (const float*)d_in[6];
  const float* gnb = (const float*)d_in[7];
  float* outp  = (float*)d_out;
  float* ctx_u = (float*)d_ws;                        // 131072 f
  float* Zsum  = ctx_u + B_ * H_ * D_ * D_;           // 4096 f
  float* stats = Zsum + B_ * HID;                     // 64 f
  unsigned* done = (unsigned*)(stats + B_ * 2);       // 32 u32
  const size_t zbytes = (size_t)(B_ * H_ * D_ * D_ + B_ * HID + B_ * 2) * sizeof(float)
                      + (size_t)B_ * sizeof(unsigned);
  hipMemsetAsync(d_ws, 0, zbytes, stream);
  hipLaunchKernelGGL(k_kv_ctx,   dim3(B_ * NSTRIP), dim3(256), 0, stream,
                     x, Wk, Wv, ctx_u, Zsum);
  hipLaunchKernelGGL(k_q_attn_o, dim3(B_ * NSTRIP), dim3(256), 0, stream,
                     x, Wq, Wo, bo, gnw, gnb, ctx_u, Zsum, stats, done, outp);
}

// Round 7
// 251.637 us; speedup vs baseline: 1.5615x; 1.1357x over previous
//
#include <hip/hip_runtime.h>

// LinearAttention fused pipeline for MI355X (gfx950) — round 11.
// Accounting across r8/r9/r10: wall - sum(kernels) ~= 70 us CONSTANT at 5/3/2
// dispatches -> fixed harness overhead; dispatch-count fusion is worthless.
// Intra-kernel cross-block barriers cost +89..+190 us (r9/r10) -> abandoned.
// r11 = r8's proven 5-dispatch skeleton (kernels sum 129 us) with ONE change:
// TPB 4->2, NSTRIP 16->32 (grid 1024). r8's occupancy was GRID-limited
// (512 blocks = 2/CU) while LDS (K2 44 KB, K1 52 KB) fits 3/CU. 1024 blocks
// -> 3 resident/CU + rolling refill -> 1.5x latency hiding for the
// latency-bound kernels (K2: 7% MFMA, 16% VALU, 25% HBM at 2/CU).
//
// ws: ctx_u[32][4][32][32] f32 | Z[32][128] f32 | stats[32][2] f32 | wb 4x16384 bf16

#define B_   32
#define C_   128
#define N_   4096
#define H_   4
#define D_   32
#define HID  128
#define NB   64
#define TPB  2        // n-tiles per block
#define NSTRIP 32     // strips per batch (NSTRIP*TPB*NB == N_)
#define STV  72       // ek/v row stride (shorts)
#define STA  136      // eqT/attnT row stride (shorts)
#define SCT  40       // ctxT row stride (shorts)
#define SCALE 0.1767766952966369f
#define EPS  1e-5f

typedef __attribute__((ext_vector_type(8))) short short8;
typedef __attribute__((ext_vector_type(4))) short short4v;
typedef __attribute__((ext_vector_type(4))) float floatx4;

__device__ __forceinline__ short f2bf(float f) {   // RNE fp32 -> bf16
  unsigned u = __float_as_uint(f);
  u += 0x7FFFu + ((u >> 16) & 1u);
  return (short)(u >> 16);
}

// load the wave's c-quarter of x tile tt into registers (32 scalar f32,
// each instr coalesces 4 rows x 64B across the wave)
#define XLOAD(tt)                                                        \
  _Pragma("unroll")                                                      \
  for (int nt = 0; nt < 4; ++nt)                                         \
    _Pragma("unroll")                                                    \
    for (int j = 0; j < 8; ++j)                                          \
      xr[nt][j] = xw[(size_t)j * N_ + (size_t)(tt) * NB + nt * 16];

// convert + write this wave's 4 fragments (lane-linear b128, conflict-free)
#define XCVT(fragbuf)                                                    \
  _Pragma("unroll")                                                      \
  for (int nt = 0; nt < 4; ++nt) {                                       \
    short8 s;                                                            \
    _Pragma("unroll")                                                    \
    for (int j = 0; j < 8; ++j) s[j] = f2bf(xr[nt][j]);                  \
    *(short8*)&fragbuf[((w * 4 + nt) * 64 + L) * 8] = s;                 \
  }

// ---------------------------------------------------------------- K0: weights -> bf16
__global__ __launch_bounds__(256) void k_wcast(
    const float* __restrict__ Wq, const float* __restrict__ Wk,
    const float* __restrict__ Wv, const float* __restrict__ Wo,
    short* __restrict__ wb) {
  const int i = blockIdx.x * 256 + threadIdx.x;   // 0..16383, 4 elems each
  const float* srcs[4] = {Wq, Wk, Wv, Wo};
#pragma unroll
  for (int m = 0; m < 4; ++m) {
    floatx4 a = ((const floatx4*)srcs[m])[i];
    short4v s = { f2bf(a[0]), f2bf(a[1]), f2bf(a[2]), f2bf(a[3]) };
    ((short4v*)(wb + m * 16384))[i] = s;
  }
}

// ---------------------------------------------------------------- K1: k,v proj + ctx/Z
__global__ __launch_bounds__(256, 2) void k_kv_ctx(
    const float* __restrict__ x, const short* __restrict__ Wkb,
    const short* __restrict__ Wvb, float* __restrict__ ctx_u,
    float* __restrict__ Zsum) {
  __shared__ short frag[8192];           // 16 KB bf16 fragment tile
  __shared__ short ekbuf[C_ * STV];      // 18 KB
  __shared__ short vbuf [C_ * STV];      // 18 KB
  const int tid = threadIdx.x;
  const int w = tid >> 6, L = tid & 63, l15 = tid & 15, q4 = (tid & 63) >> 4;
  const int b = blockIdx.x / NSTRIP;
  const int strip = blockIdx.x % NSTRIP;
  const float* xw = x + (size_t)b * (C_ * N_) + (size_t)(w * 32 + q4 * 8) * N_
                      + (size_t)(strip * TPB) * NB + l15;

  short8 ak[2][4], av[2][4];
#pragma unroll
  for (int mt = 0; mt < 2; ++mt)
#pragma unroll
    for (int ks = 0; ks < 4; ++ks) {
      ak[mt][ks] = *(const short8*)&Wkb[(w * 32 + mt * 16 + l15) * C_ + ks * 32 + q4 * 8];
      av[mt][ks] = *(const short8*)&Wvb[(w * 32 + mt * 16 + l15) * C_ + ks * 32 + q4 * 8];
    }

  const floatx4 z4 = {0.f, 0.f, 0.f, 0.f};
  floatx4 ca[2][2] = {{z4, z4}, {z4, z4}};   // ctx accumulator across tiles
  float zreg[2][4] = {{0.f,0.f,0.f,0.f},{0.f,0.f,0.f,0.f}};
  float xr[4][8];

  // prologue: tile0 -> regs -> frag; issue tile1 loads
  XLOAD(0)
  XCVT(frag)
  XLOAD(1)

  for (int t = 0; t < TPB; ++t) {
    __syncthreads();   // b1: frag(t) visible

    // ---- k GEMM (acck live only until pack-ek below)
    floatx4 acck[2][4];
#pragma unroll
    for (int mt = 0; mt < 2; ++mt)
#pragma unroll
      for (int nt = 0; nt < 4; ++nt) acck[mt][nt] = z4;
#pragma unroll
    for (int ks = 0; ks < 4; ++ks) {
      short8 Bf[4];
#pragma unroll
      for (int nt = 0; nt < 4; ++nt)
        Bf[nt] = *(const short8*)&frag[((ks * 4 + nt) * 64 + L) * 8];
#pragma unroll
      for (int mt = 0; mt < 2; ++mt)
#pragma unroll
        for (int nt = 0; nt < 4; ++nt)
          acck[mt][nt] = __builtin_amdgcn_mfma_f32_16x16x32_bf16(ak[mt][ks], Bf[nt], acck[mt][nt], 0, 0, 0);
    }

    // exp(k) + Z partial accumulation + pack ek (kills acck)
#pragma unroll
    for (int mt = 0; mt < 2; ++mt)
#pragma unroll
      for (int nt = 0; nt < 4; ++nt)
#pragma unroll
        for (int r = 0; r < 4; ++r)
          acck[mt][nt][r] = __expf(acck[mt][nt][r]);
#pragma unroll
    for (int mt = 0; mt < 2; ++mt)
#pragma unroll
      for (int r = 0; r < 4; ++r)
        zreg[mt][r] += acck[mt][0][r] + acck[mt][1][r] + acck[mt][2][r] + acck[mt][3][r];
#pragma unroll
    for (int mt = 0; mt < 2; ++mt)
#pragma unroll
      for (int nt = 0; nt < 4; ++nt)
#pragma unroll
        for (int r = 0; r < 4; ++r)
          ekbuf[(w * 32 + mt * 16 + q4 * 4 + r) * STV + nt * 16 + l15] = f2bf(acck[mt][nt][r]);

    // ---- v GEMM (accv born after acck dead; re-reads frag, conflict-free)
    floatx4 accv[2][4];
#pragma unroll
    for (int mt = 0; mt < 2; ++mt)
#pragma unroll
      for (int nt = 0; nt < 4; ++nt) accv[mt][nt] = z4;
#pragma unroll
    for (int ks = 0; ks < 4; ++ks) {
      short8 Bf[4];
#pragma unroll
      for (int nt = 0; nt < 4; ++nt)
        Bf[nt] = *(const short8*)&frag[((ks * 4 + nt) * 64 + L) * 8];
#pragma unroll
      for (int mt = 0; mt < 2; ++mt)
#pragma unroll
        for (int nt = 0; nt < 4; ++nt)
          accv[mt][nt] = __builtin_amdgcn_mfma_f32_16x16x32_bf16(av[mt][ks], Bf[nt], accv[mt][nt], 0, 0, 0);
    }
    __syncthreads();   // b2: all frag reads done -> rewrite allowed

    // convert regs (tile t+1) -> frag; issue loads for tile t+2
    if (t + 1 < TPB) {
      XCVT(frag)
      if (t + 2 < TPB) { XLOAD(t + 2) }
    }

    // pack v (wave-local rows, in-wave DS ordering)
#pragma unroll
    for (int mt = 0; mt < 2; ++mt)
#pragma unroll
      for (int nt = 0; nt < 4; ++nt)
#pragma unroll
        for (int r = 0; r < 4; ++r)
          vbuf[(w * 32 + mt * 16 + q4 * 4 + r) * STV + nt * 16 + l15] = f2bf(accv[mt][nt][r]);

    // ctx partial via MFMA (wave-local rows), accumulates across tiles
#pragma unroll
    for (int ks = 0; ks < 2; ++ks) {
      short8 ae[2], be[2];
#pragma unroll
      for (int mt = 0; mt < 2; ++mt)
        ae[mt] = *(const short8*)&ekbuf[(w * 32 + mt * 16 + l15) * STV + ks * 32 + q4 * 8];
#pragma unroll
      for (int nt = 0; nt < 2; ++nt)
        be[nt] = *(const short8*)&vbuf[(w * 32 + nt * 16 + l15) * STV + ks * 32 + q4 * 8];
#pragma unroll
      for (int mt = 0; mt < 2; ++mt)
#pragma unroll
        for (int nt = 0; nt < 2; ++nt)
          ca[mt][nt] = __builtin_amdgcn_mfma_f32_16x16x32_bf16(ae[mt], be[nt], ca[mt][nt], 0, 0, 0);
    }
  }

  // Z: reduce over l15, one atomic per row
#pragma unroll
  for (int mt = 0; mt < 2; ++mt)
#pragma unroll
    for (int r = 0; r < 4; ++r) {
      float s = zreg[mt][r];
      s += __shfl_xor(s, 1); s += __shfl_xor(s, 2);
      s += __shfl_xor(s, 4); s += __shfl_xor(s, 8);
      if (l15 == 0) atomicAdd(&Zsum[b * HID + w * 32 + mt * 16 + q4 * 4 + r], s);
    }

  // ctx atomics (once per block)
  float* cb = &ctx_u[((size_t)b * H_ + w) * (D_ * D_)];
#pragma unroll
  for (int mt = 0; mt < 2; ++mt)
#pragma unroll
    for (int nt = 0; nt < 2; ++nt)
#pragma unroll
      for (int r = 0; r < 4; ++r)
        atomicAdd(&cb[(mt * 16 + q4 * 4 + r) * D_ + nt * 16 + l15], ca[mt][nt][r]);
}

// ---------------------------------------------------------------- K2: q proj + attn + Wo + stats
__global__ __launch_bounds__(256, 2) void k_q_attn_o(
    const float* __restrict__ x, const short* __restrict__ Wqb,
    const short* __restrict__ Wob, const float* __restrict__ bo,
    const float* __restrict__ ctx_u, const float* __restrict__ Zsum,
    float* __restrict__ outp, float* __restrict__ stats) {
  __shared__ short frag[8192];        // 16 KB bf16 fragment tile
  __shared__ short qat[NB * STA];     // eq^T then attn^T, 17 KB
  __shared__ short ctxT[HID * SCT];   // 10 KB
  const int tid = threadIdx.x;
  const int w = tid >> 6, L = tid & 63, l15 = tid & 15, q4 = (tid & 63) >> 4;
  const int b = blockIdx.x / NSTRIP;
  const int strip = blockIdx.x % NSTRIP;
  const float* xw = x + (size_t)b * (C_ * N_) + (size_t)(w * 32 + q4 * 8) * N_
                      + (size_t)(strip * TPB) * NB + l15;

  // prologue: tile0 -> regs -> frag; issue tile1 loads; ctxT fill overlaps
  float xr[4][8];
  XLOAD(0)
  XCVT(frag)
  XLOAD(1)
#pragma unroll
  for (int i = 0; i < 16; ++i) {
    const int idx = tid + i * 256;               // h*1024 + d*32 + e
    float v = ctx_u[(size_t)b * (H_ * D_ * D_) + idx] *
              __builtin_amdgcn_rcpf(Zsum[b * HID + (idx >> 5)]);
    ctxT[((idx >> 10) * 32 + (idx & 31)) * SCT + ((idx >> 5) & 31)] = f2bf(v);
  }

  short8 aq[2][4], ao[2][4];
#pragma unroll
  for (int mt = 0; mt < 2; ++mt)
#pragma unroll
    for (int ks = 0; ks < 4; ++ks) {
      aq[mt][ks] = *(const short8*)&Wqb[(w * 32 + mt * 16 + l15) * C_ + ks * 32 + q4 * 8];
      ao[mt][ks] = *(const short8*)&Wob[(w * 32 + mt * 16 + l15) * HID + ks * 32 + q4 * 8];
    }

  const floatx4 z4 = {0.f, 0.f, 0.f, 0.f};
  float s1 = 0.f, s2 = 0.f;

  for (int t = 0; t < TPB; ++t) {
    const int n0 = (strip * TPB + t) * NB;
    __syncthreads();   // b1: frag(t) + (t==0) ctxT visible

    // q = Wq @ x — B-frags are lane-linear ds_read_b128, no converts
    floatx4 acc[2][4];
#pragma unroll
    for (int mt = 0; mt < 2; ++mt)
#pragma unroll
      for (int nt = 0; nt < 4; ++nt) acc[mt][nt] = z4;
#pragma unroll
    for (int ks = 0; ks < 4; ++ks) {
      short8 Bf[4];
#pragma unroll
      for (int nt = 0; nt < 4; ++nt)
        Bf[nt] = *(const short8*)&frag[((ks * 4 + nt) * 64 + L) * 8];
#pragma unroll
      for (int mt = 0; mt < 2; ++mt)
#pragma unroll
        for (int nt = 0; nt < 4; ++nt)
          acc[mt][nt] = __builtin_amdgcn_mfma_f32_16x16x32_bf16(aq[mt][ks], Bf[nt], acc[mt][nt], 0, 0, 0);
    }
    __syncthreads();   // b2: frag reads done -> rewrite allowed

    // convert regs (tile t+1) -> frag; issue loads for tile t+2
    if (t + 1 < TPB) {
      XCVT(frag)
      if (t + 2 < TPB) { XLOAD(t + 2) }
    }

    // exp(q); per-column softmax denom via shuffle
#pragma unroll
    for (int mt = 0; mt < 2; ++mt)
#pragma unroll
      for (int nt = 0; nt < 4; ++nt)
#pragma unroll
        for (int r = 0; r < 4; ++r)
          acc[mt][nt][r] = __expf(acc[mt][nt][r]);
    float inv[4];
#pragma unroll
    for (int nt = 0; nt < 4; ++nt) {
      float s = 0.f;
#pragma unroll
      for (int mt = 0; mt < 2; ++mt)
#pragma unroll
        for (int r = 0; r < 4; ++r) s += acc[mt][nt][r];
      s += __shfl_xor(s, 16); s += __shfl_xor(s, 32);
      inv[nt] = SCALE * __builtin_amdgcn_rcpf(s);
    }

    // scaled eq^T into qat (wave-local columns)
#pragma unroll
    for (int mt = 0; mt < 2; ++mt)
#pragma unroll
      for (int nt = 0; nt < 4; ++nt) {
        short4v pk = { f2bf(acc[mt][nt][0] * inv[nt]), f2bf(acc[mt][nt][1] * inv[nt]),
                       f2bf(acc[mt][nt][2] * inv[nt]), f2bf(acc[mt][nt][3] * inv[nt]) };
        *(short4v*)&qat[(nt * 16 + l15) * STA + w * 32 + mt * 16 + q4 * 4] = pk;
      }

    // attn: out[e][n] = sum_d ctxT[e][d] * eq[d][n]   (wave-local)
    {
      floatx4 aacc[2][4];
#pragma unroll
      for (int mt = 0; mt < 2; ++mt)
#pragma unroll
        for (int nt = 0; nt < 4; ++nt) aacc[mt][nt] = z4;
      short8 ae[2];
#pragma unroll
      for (int mt = 0; mt < 2; ++mt)
        ae[mt] = *(const short8*)&ctxT[(w * 32 + mt * 16 + l15) * SCT + q4 * 8];
#pragma unroll
      for (int nt = 0; nt < 4; ++nt) {
        short8 bq = *(const short8*)&qat[(nt * 16 + l15) * STA + w * 32 + q4 * 8];
#pragma unroll
        for (int mt = 0; mt < 2; ++mt)
          aacc[mt][nt] = __builtin_amdgcn_mfma_f32_16x16x32_bf16(ae[mt], bq, aacc[mt][nt], 0, 0, 0);
      }
      // attn^T over eq^T (same wave-local columns)
#pragma unroll
      for (int nt = 0; nt < 4; ++nt)
#pragma unroll
        for (int mt = 0; mt < 2; ++mt) {
          short4v pk = { f2bf(aacc[mt][nt][0]), f2bf(aacc[mt][nt][1]),
                         f2bf(aacc[mt][nt][2]), f2bf(aacc[mt][nt][3]) };
          *(short4v*)&qat[(nt * 16 + l15) * STA + w * 32 + mt * 16 + q4 * 4] = pk;
        }
    }
    __syncthreads();   // b3: attn^T visible to all waves

    // out_pre = Wo @ attn + bo
    floatx4 oacc[2][4];
#pragma unroll
    for (int mt = 0; mt < 2; ++mt)
#pragma unroll
      for (int nt = 0; nt < 4; ++nt) oacc[mt][nt] = z4;
#pragma unroll
    for (int ks = 0; ks < 4; ++ks) {
      short8 bf8[4];
#pragma unroll
      for (int nt = 0; nt < 4; ++nt)
        bf8[nt] = *(const short8*)&qat[(nt * 16 + l15) * STA + ks * 32 + q4 * 8];
#pragma unroll
      for (int mt = 0; mt < 2; ++mt)
#pragma unroll
        for (int nt = 0; nt < 4; ++nt)
          oacc[mt][nt] = __builtin_amdgcn_mfma_f32_16x16x32_bf16(ao[mt][ks], bf8[nt], oacc[mt][nt], 0, 0, 0);
    }

    // epilogue: +bo, store, accumulate stats in registers
#pragma unroll
    for (int mt = 0; mt < 2; ++mt) {
      const int rowbase = w * 32 + mt * 16 + q4 * 4;
      const floatx4 bo4 = *(const floatx4*)&bo[rowbase];
#pragma unroll
      for (int nt = 0; nt < 4; ++nt) {
        const int n = n0 + nt * 16 + l15;
#pragma unroll
        for (int r = 0; r < 4; ++r) {
          float vv = oacc[mt][nt][r] + bo4[r];
          outp[(size_t)b * (C_ * N_) + (size_t)(rowbase + r) * N_ + n] = vv;
          s1 += vv; s2 += vv * vv;
        }
      }
    }
  }

  // stats: wave reduce + one atomic pair per wave
#pragma unroll
  for (int m = 1; m < 64; m <<= 1) {
    s1 += __shfl_xor(s1, m);
    s2 += __shfl_xor(s2, m);
  }
  if ((tid & 63) == 0) {
    atomicAdd(&stats[b * 2 + 0], s1);
    atomicAdd(&stats[b * 2 + 1], s2);
  }
}

// ---------------------------------------------------------------- K3: GroupNorm
__global__ __launch_bounds__(256) void k_gnorm(
    float* __restrict__ outp, const float* __restrict__ stats,
    const float* __restrict__ gnw, const float* __restrict__ gnb) {
  const int b = blockIdx.x >> 6;
  const int blk = blockIdx.x & 63;
  const float M = (float)(C_ * N_);
  const float mu = stats[b * 2 + 0] / M;
  const float var = stats[b * 2 + 1] / M - mu * mu;
  const float rs = rsqrtf(var + EPS);
  floatx4* p = (floatx4*)(outp + (size_t)b * (C_ * N_) + (size_t)blk * 8192);
  const int tid = threadIdx.x;
#pragma unroll
  for (int i = 0; i < 8; ++i) {
    const int idx = tid + i * 256;
    const int fl = blk * 8192 + idx * 4;
    const int c = fl >> 12;
    const float wgt = gnw[c] * rs;
    const float bia = gnb[c] - mu * wgt;
    floatx4 v = p[idx];
    v[0] = v[0] * wgt + bia;
    v[1] = v[1] * wgt + bia;
    v[2] = v[2] * wgt + bia;
    v[3] = v[3] * wgt + bia;
    p[idx] = v;
  }
}

// ---------------------------------------------------------------- launch
extern "C" void kernel_launch(void* const* d_in, const int* in_sizes, int n_in,
                              void* d_out, int out_size, void* d_ws, size_t ws_size,
                              hipStream_t stream) {
  (void)in_sizes; (void)n_in; (void)out_size; (void)ws_size;
  const float* x   = (const float*)d_in[0];
  const float* Wq  = (const float*)d_in[1];
  const float* Wk  = (const float*)d_in[2];
  const float* Wv  = (const float*)d_in[3];
  const float* Wo  = (const float*)d_in[4];
  const float* bo  = (const float*)d_in[5];
  const float* gnw = (const float*)d_in[6];
  const float* gnb = (const float*)d_in[7];
  float* outp  = (float*)d_out;
  float* ctx_u = (float*)d_ws;                       // 131072 f
  float* Zsum  = ctx_u + B_ * H_ * D_ * D_;          // 4096 f
  float* stats = Zsum + B_ * HID;                    // 64 f
  short* wb    = (short*)(stats + B_ * 2);           // 4 x 16384 bf16
  const size_t zbytes = (size_t)(B_ * H_ * D_ * D_ + B_ * HID + B_ * 2) * sizeof(float);
  hipMemsetAsync(d_ws, 0, zbytes, stream);
  hipLaunchKernelGGL(k_wcast,    dim3(64),          dim3(256), 0, stream, Wq, Wk, Wv, Wo, wb);
  hipLaunchKernelGGL(k_kv_ctx,   dim3(B_ * NSTRIP), dim3(256), 0, stream, x, wb + 16384, wb + 32768, ctx_u, Zsum);
  hipLaunchKernelGGL(k_q_attn_o, dim3(B_ * NSTRIP), dim3(256), 0, stream, x, wb, wb + 49152, bo, ctx_u, Zsum, outp, stats);
  hipLaunchKernelGGL(k_gnorm,    dim3(B_ * 64),     dim3(256), 0, stream, outp, stats, gnw, gnb);
}